// Round 1
// baseline (2056.321 us; speedup 1.0000x reference)
//
#include <hip/hip_runtime.h>

// out[a[i]] += Aval[c[i]] * Bval[d[i]]  for i in [0, M), rows of D=32 fp32.
// acd is (3, M) int32 row-major: a = acd[i], c = acd[M+i], d = acd[2M+i].
//
// Layout: 8 threads per pair, each thread owns a float4 (4 features).
// Lane -> feature mapping keeps each pair's 128 B row contiguous/coalesced.

#define FEAT_D 32

__global__ __launch_bounds__(256) void spspmm_scatter_kernel(
    const float* __restrict__ Aval,
    const float* __restrict__ Bval,
    const int* __restrict__ acd,
    float* __restrict__ out,
    int M)
{
    int gid = blockIdx.x * blockDim.x + threadIdx.x;
    int pair = gid >> 3;       // 8 threads per pair
    int f4   = gid & 7;        // which float4 of the 32-float row
    if (pair >= M) return;

    int a = acd[pair];
    int c = acd[M + pair];
    int d = acd[2 * M + pair];

    const float4 av = *reinterpret_cast<const float4*>(Aval + (size_t)c * FEAT_D + f4 * 4);
    const float4 bv = *reinterpret_cast<const float4*>(Bval + (size_t)d * FEAT_D + f4 * 4);

    float* o = out + (size_t)a * FEAT_D + f4 * 4;
    atomicAdd(o + 0, av.x * bv.x);
    atomicAdd(o + 1, av.y * bv.y);
    atomicAdd(o + 2, av.z * bv.z);
    atomicAdd(o + 3, av.w * bv.w);
}

extern "C" void kernel_launch(void* const* d_in, const int* in_sizes, int n_in,
                              void* d_out, int out_size, void* d_ws, size_t ws_size,
                              hipStream_t stream) {
    const float* Aval = (const float*)d_in[0];
    const float* Bval = (const float*)d_in[1];
    const int*   acd  = (const int*)d_in[2];
    float*       out  = (float*)d_out;

    const int M = in_sizes[2] / 3;

    // d_out is poisoned to 0xAA before every timed launch; we accumulate with
    // atomics, so zero it first (stream-ordered, graph-capture safe).
    hipMemsetAsync(d_out, 0, (size_t)out_size * sizeof(float), stream);

    const long long total_threads = (long long)M * 8;
    const int block = 256;
    const long long grid = (total_threads + block - 1) / block;
    spspmm_scatter_kernel<<<dim3((unsigned)grid), dim3(block), 0, stream>>>(
        Aval, Bval, acd, out, M);
}

// Round 2
// 1424.220 us; speedup vs baseline: 1.4438x; 1.4438x over previous
//
#include <hip/hip_runtime.h>

// out[a[i]] += Aval[c[i]] * Bval[d[i]]  for i in [0, M), rows of D=32 fp32.
// acd is (3, M) int32 row-major: a = acd[i], c = acd[M+i], d = acd[2M+i].
//
// Strategy (round 2): the round-1 global-atomic scatter showed 8x HBM write
// amplification (2 GB writes for a 256 MB output) — atomic RMW misses L2.
// Replace with: partition pairs by output bucket (512 rows/bucket), then one
// block per bucket accumulates into LDS (ds_add_f32) and writes the tile out
// once with plain coalesced stores. Zero global atomics on the output.

#define FEAT_D 32
#define BUCKET_BITS 9
#define BUCKET_ROWS (1 << BUCKET_BITS)       // 512 rows per bucket
#define ROW_STRIDE 33                        // pad: stride % 4 == 1 -> spreads LDS banks
#define MAX_BINS 4096

typedef unsigned int u32;
typedef unsigned long long u64;

// ---------------- K1: histogram of bucket ids ----------------
__global__ __launch_bounds__(256) void hist_kernel(
    const int* __restrict__ acd, u32* __restrict__ ghist, int M, int NB)
{
    __shared__ u32 lh[MAX_BINS];
    for (int i = threadIdx.x; i < NB; i += blockDim.x) lh[i] = 0;
    __syncthreads();
    int stride = gridDim.x * blockDim.x;
    for (int i = blockIdx.x * blockDim.x + threadIdx.x; i < M; i += stride) {
        int a = acd[i];
        atomicAdd(&lh[a >> BUCKET_BITS], 1u);
    }
    __syncthreads();
    for (int i = threadIdx.x; i < NB; i += blockDim.x)
        if (lh[i]) atomicAdd(&ghist[i], lh[i]);
}

// ---------------- K2: exclusive scan (single block, 1024 threads) ----------------
__global__ __launch_bounds__(1024) void scan_kernel(
    const u32* __restrict__ ghist, u32* __restrict__ offsets,
    u32* __restrict__ cursors, int NB)
{
    __shared__ u32 partial[1024];
    int t = threadIdx.x;
    const int PER = 4;  // 1024*4 = 4096 >= NB
    u32 v[PER];
    u32 sum = 0;
    for (int k = 0; k < PER; k++) {
        int i = t * PER + k;
        v[k] = (i < NB) ? ghist[i] : 0u;
        sum += v[k];
    }
    partial[t] = sum;
    __syncthreads();
    // Hillis-Steele inclusive scan over partial[1024]
    for (int off = 1; off < 1024; off <<= 1) {
        u32 mine = partial[t];
        u32 add = (t >= off) ? partial[t - off] : 0u;
        __syncthreads();
        partial[t] = mine + add;
        __syncthreads();
    }
    u32 running = (t == 0) ? 0u : partial[t - 1];
    for (int k = 0; k < PER; k++) {
        int i = t * PER + k;
        if (i < NB) {
            offsets[i] = running;
            cursors[i] = running;
        }
        running += v[k];
    }
    if (t == 0) offsets[NB] = partial[1023];
}

// ---------------- K3: scatter packed records into bucket order ----------------
__global__ __launch_bounds__(256) void scatter_kernel(
    const int* __restrict__ acd, u32* __restrict__ cursors,
    u64* __restrict__ rec, int M)
{
    int stride = gridDim.x * blockDim.x;
    for (int i = blockIdx.x * blockDim.x + threadIdx.x; i < M; i += stride) {
        u32 a = (u32)acd[i];
        u32 c = (u32)acd[M + i];
        u32 d = (u32)acd[2 * M + i];
        u32 b = a >> BUCKET_BITS;
        u32 pos = atomicAdd(&cursors[b], 1u);
        // word0: c (21b) | a_low (9b) << 21 ; word1: d (21b)
        rec[pos] = ((u64)d << 32) | (u64)(c | ((a & (BUCKET_ROWS - 1)) << 21));
    }
}

// ---------------- K4: per-bucket LDS accumulate + contiguous store ----------------
__global__ __launch_bounds__(512) void accum_kernel(
    const u64* __restrict__ rec, const u32* __restrict__ offsets,
    const float* __restrict__ Aval, const float* __restrict__ Bval,
    float* __restrict__ out, int tar)
{
    __shared__ float acc[BUCKET_ROWS * ROW_STRIDE];  // 512*33*4 = 67.6 KB
    int t = threadIdx.x;
    int b = blockIdx.x;
    for (int i = t; i < BUCKET_ROWS * ROW_STRIDE; i += 512) acc[i] = 0.f;
    __syncthreads();

    u32 s = offsets[b], e = offsets[b + 1];
    int g  = t >> 3;   // 64 groups per block
    int f4 = t & 7;    // float4 slot within the 32-float row
    for (u32 idx = s + g; idx < e; idx += 64) {
        u64 r = rec[idx];
        u32 w0 = (u32)r;
        u32 d  = (u32)(r >> 32);
        u32 c  = w0 & 0x1FFFFFu;
        u32 al = (w0 >> 21) & (BUCKET_ROWS - 1);
        const float4 av = *reinterpret_cast<const float4*>(Aval + (size_t)c * FEAT_D + f4 * 4);
        const float4 bv = *reinterpret_cast<const float4*>(Bval + (size_t)d * FEAT_D + f4 * 4);
        float* p = &acc[al * ROW_STRIDE + f4 * 4];
        atomicAdd(p + 0, av.x * bv.x);
        atomicAdd(p + 1, av.y * bv.y);
        atomicAdd(p + 2, av.z * bv.z);
        atomicAdd(p + 3, av.w * bv.w);
    }
    __syncthreads();

    // write out: rows [b*512, min(tar, b*512+512))
    int row0 = b << BUCKET_BITS;
    int nrows = tar - row0;
    if (nrows > BUCKET_ROWS) nrows = BUCKET_ROWS;
    int nel = nrows * FEAT_D;
    float* obase = out + (size_t)row0 * FEAT_D;
    for (int i = t; i < nel; i += 512) {
        int row = i >> 5, col = i & 31;
        obase[i] = acc[row * ROW_STRIDE + col];
    }
}

// ---------------- round-1 fallback (global atomics) ----------------
__global__ __launch_bounds__(256) void spspmm_scatter_kernel(
    const float* __restrict__ Aval, const float* __restrict__ Bval,
    const int* __restrict__ acd, float* __restrict__ out, int M)
{
    int gid = blockIdx.x * blockDim.x + threadIdx.x;
    int pair = gid >> 3;
    int f4 = gid & 7;
    if (pair >= M) return;
    int a = acd[pair];
    int c = acd[M + pair];
    int d = acd[2 * M + pair];
    const float4 av = *reinterpret_cast<const float4*>(Aval + (size_t)c * FEAT_D + f4 * 4);
    const float4 bv = *reinterpret_cast<const float4*>(Bval + (size_t)d * FEAT_D + f4 * 4);
    float* o = out + (size_t)a * FEAT_D + f4 * 4;
    atomicAdd(o + 0, av.x * bv.x);
    atomicAdd(o + 1, av.y * bv.y);
    atomicAdd(o + 2, av.z * bv.z);
    atomicAdd(o + 3, av.w * bv.w);
}

extern "C" void kernel_launch(void* const* d_in, const int* in_sizes, int n_in,
                              void* d_out, int out_size, void* d_ws, size_t ws_size,
                              hipStream_t stream) {
    const float* Aval = (const float*)d_in[0];
    const float* Bval = (const float*)d_in[1];
    const int*   acd  = (const int*)d_in[2];
    float*       out  = (float*)d_out;

    const int M   = in_sizes[2] / 3;
    const int tar = out_size / FEAT_D;
    const int NB  = (tar + BUCKET_ROWS - 1) >> BUCKET_BITS;

    // workspace layout: rec[M] (8B each) | ghist[NB] | offsets[NB+1] | cursors[NB]
    size_t rec_bytes = (size_t)M * sizeof(u64);
    size_t need = rec_bytes + (size_t)(3 * NB + 2) * sizeof(u32) + 256;

    if (NB <= MAX_BINS && ws_size >= need) {
        u64* rec     = (u64*)d_ws;
        u32* ghist   = (u32*)((char*)d_ws + rec_bytes);
        u32* offsets = ghist + NB;
        u32* cursors = offsets + (NB + 1);

        hipMemsetAsync(ghist, 0, (size_t)NB * sizeof(u32), stream);
        hist_kernel<<<1024, 256, 0, stream>>>(acd, ghist, M, NB);
        scan_kernel<<<1, 1024, 0, stream>>>(ghist, offsets, cursors, NB);
        scatter_kernel<<<2048, 256, 0, stream>>>(acd, cursors, rec, M);
        accum_kernel<<<NB, 512, 0, stream>>>(rec, offsets, Aval, Bval, out, tar);
    } else {
        hipMemsetAsync(d_out, 0, (size_t)out_size * sizeof(float), stream);
        const long long total_threads = (long long)M * 8;
        const long long grid = (total_threads + 255) / 256;
        spspmm_scatter_kernel<<<dim3((unsigned)grid), dim3(256), 0, stream>>>(
            Aval, Bval, acd, out, M);
    }
}